// Round 5
// baseline (90.455 us; speedup 1.0000x reference)
//
#include <hip/hip_runtime.h>
#include <hip/hip_bf16.h>

#define BB 16
#define HH 512
#define WW 512
#define NVV 35709
#define NTT 70000
#define HWW (HH * WW)

// World model (R0-R4 forensics):
//   proj_geo, texture, nbl, ori_img : float32   (R1 bf16-read gave NaN => f32)
//   is_visible, tri_inds, pixel_valid : int32
//   OUTPUT: float32  (R2 had correct f32 inputs + bf16 writes and failed =>
//           harness reads f32; "bf16" in test label is template text)
//   Outputs concatenated flat: render [B,H,W,3] then real [B,H,W,3].

__global__ __launch_bounds__(256) void zero_kernel(float4* __restrict__ p, long n4)
{
    long i = (long)blockIdx.x * blockDim.x + threadIdx.x;
    long stride = (long)gridDim.x * blockDim.x;
    float4 z = {0.f, 0.f, 0.f, 0.f};
    for (; i < n4; i += stride) p[i] = z;
}

__global__ __launch_bounds__(256) void splat_kernel(
    const float* __restrict__ proj,
    const float* __restrict__ tex,
    const float* __restrict__ nbl,
    const int* __restrict__ vis,
    const int* __restrict__ tri,
    float* __restrict__ csum,
    float* __restrict__ wsum,
    int b0)
{
    int t = blockIdx.x * blockDim.x + threadIdx.x;
    if (t >= NTT) return;
    int bl = blockIdx.y;          // local batch index within this pass
    int b = b0 + bl;              // global batch

    int i0 = tri[t * 3 + 0];
    int i1 = tri[t * 3 + 1];
    int i2 = tri[t * 3 + 2];

    int base = b * NVV;
    // tri_w = min(vis) over {0,1}; zero-weight triangles contribute nothing.
    if (vis[base + i0] == 0 || vis[base + i1] == 0 || vis[base + i2] == 0) return;

    long p0 = (long)(base + i0) * 3;
    long p1 = (long)(base + i1) * 3;
    long p2 = (long)(base + i2) * 3;

    float x0 = proj[p0 + 0], y0 = proj[p0 + 1];
    float x1 = proj[p1 + 0], y1 = proj[p1 + 1];
    float x2 = proj[p2 + 0], y2 = proj[p2 + 1];

    float fx = ((x0 + x1) + x2) / 3.0f;   // numpy f32 pairwise sum + true_divide
    float fy = ((y0 + y1) + y2) / 3.0f;

    int px = (int)rintf(fx);              // np.round = round-half-even
    int py = (int)rintf(fy);
    px = min(max(px, 0), WW - 1);
    py = min(max(py, 0), HH - 1);

    float c0r = tex[p0 + 0] * nbl[p0 + 0];
    float c0g = tex[p0 + 1] * nbl[p0 + 1];
    float c0b = tex[p0 + 2] * nbl[p0 + 2];
    float c1r = tex[p1 + 0] * nbl[p1 + 0];
    float c1g = tex[p1 + 1] * nbl[p1 + 1];
    float c1b = tex[p1 + 2] * nbl[p1 + 2];
    float c2r = tex[p2 + 0] * nbl[p2 + 0];
    float c2g = tex[p2 + 1] * nbl[p2 + 1];
    float c2b = tex[p2 + 2] * nbl[p2 + 2];

    float cr = ((c0r + c1r) + c2r) / 3.0f;
    float cg = ((c0g + c1g) + c2g) / 3.0f;
    float cb = ((c0b + c1b) + c2b) / 3.0f;

    long lin = (long)bl * HWW + (long)py * WW + px;   // LOCAL accumulator index
    atomicAdd(&csum[lin * 3 + 0], cr);
    atomicAdd(&csum[lin * 3 + 1], cg);
    atomicAdd(&csum[lin * 3 + 2], cb);
    atomicAdd(&wsum[lin], 1.0f);
}

__global__ __launch_bounds__(256) void compose_kernel(
    const float* __restrict__ csum,
    const float* __restrict__ wsum,
    const float* __restrict__ ori,
    const int* __restrict__ pvalid,
    float* __restrict__ out,
    int b0, int nb)
{
    long il = (long)blockIdx.x * blockDim.x + threadIdx.x;   // local pixel idx
    if (il >= (long)nb * HWW) return;
    long ig = (long)b0 * HWW + il;                           // global pixel idx

    float w = wsum[il];
    bool pv = pvalid[ig] > 0;
    bool covered = (w > 0.0f) && pv;
    float denom = fmaxf(w, 1.0f);

    const long ROFF = (long)BB * HWW * 3;   // f32 elements: offset of `real`

#pragma unroll
    for (int c = 0; c < 3; ++c) {
        float oi = ori[ig * 3 + c];
        float face = csum[il * 3 + c] / denom;
        float render = covered ? face : oi;
        float real = pv ? oi : 0.0f;
        out[ig * 3 + c] = render;
        out[ROFF + ig * 3 + c] = real;
    }
}

extern "C" void kernel_launch(void* const* d_in, const int* in_sizes, int n_in,
                              void* d_out, int out_size, void* d_ws, size_t ws_size,
                              hipStream_t stream) {
    const float* proj = (const float*)d_in[0];
    const float* tex  = (const float*)d_in[1];
    const float* nbl  = (const float*)d_in[2];
    const float* ori  = (const float*)d_in[3];
    const int* vis    = (const int*)d_in[4];
    const int* tri    = (const int*)d_in[5];
    const int* pvalid = (const int*)d_in[6];
    float* out        = (float*)d_out;

    // Batches per pass bounded by workspace: 4 f32 per pixel (csum rgb + wsum).
    const size_t perBatchBytes = (size_t)HWW * 4 * sizeof(float);   // 4 MiB
    int nbMax = (int)(ws_size / perBatchBytes);
    if (nbMax < 1) nbMax = 1;
    if (nbMax > BB) nbMax = BB;

    for (int b0 = 0; b0 < BB; b0 += nbMax) {
        int nb = (BB - b0 < nbMax) ? (BB - b0) : nbMax;

        float* csum = (float*)d_ws;                         // nb*HW*3 f32
        float* wsum = csum + (size_t)nb * HWW * 3;          // nb*HW f32

        long n4 = (long)nb * HWW;                           // (nb*HW*4)/4 float4s
        int zblocks = (int)((n4 + 255) / 256);
        if (zblocks > 4096) zblocks = 4096;
        zero_kernel<<<zblocks, 256, 0, stream>>>((float4*)d_ws, n4);

        dim3 gs((NTT + 255) / 256, nb);
        splat_kernel<<<gs, 256, 0, stream>>>(proj, tex, nbl, vis, tri, csum, wsum, b0);

        long npix = (long)nb * HWW;
        compose_kernel<<<(int)((npix + 255) / 256), 256, 0, stream>>>(
            csum, wsum, ori, pvalid, out, b0, nb);
    }
}